// Round 2
// baseline (176.599 us; speedup 1.0000x reference)
//
#include <hip/hip_runtime.h>
#include <hip/hip_bf16.h>

#define NUM_CLASSES 7
#define ROWS_PER_TILE 256
#define BLOCK 256
#define NBLOCKS 2048
#define F4_PER_TILE (ROWS_PER_TILE * NUM_CLASSES / 4)   // 448

// Main kernel: per-block tiles of 256 rows staged through LDS with coalesced
// float4 loads; per-row 7-class softmax-window loss; per-block double partial.
__global__ __launch_bounds__(BLOCK) void pom_main(const float* __restrict__ logits,
                                                  const int* __restrict__ targets,
                                                  double* __restrict__ partials,
                                                  int B) {
    // 448 float4 = 7168 B of LDS; 16B-aligned for float4 stores.
    __shared__ float4 tile4[F4_PER_TILE];
    float* tile = (float*)tile4;

    const int tid = threadIdx.x;
    const int numTiles = (B + ROWS_PER_TILE - 1) / ROWS_PER_TILE;
    const float4* __restrict__ g4 = (const float4*)logits;
    const long long totalF4 = ((long long)B * NUM_CLASSES) / 4;  // 7M for B=4M

    float acc = 0.0f;  // per-thread loss accumulator (~8 rows, f32 is plenty)

    for (int t = blockIdx.x; t < numTiles; t += gridDim.x) {
        const long long f4base = (long long)t * F4_PER_TILE;
        const int row = t * ROWS_PER_TILE + tid;

        // Issue all three HBM loads into registers BEFORE the barrier so HBM
        // latency overlaps the previous tile's compute.
        int tg = 0;
        if (row < B) tg = targets[row];
        float4 a = make_float4(0.f, 0.f, 0.f, 0.f);
        float4 b = make_float4(0.f, 0.f, 0.f, 0.f);
        if (f4base + tid < totalF4)        a = g4[f4base + tid];
        if (tid < F4_PER_TILE - BLOCK && f4base + BLOCK + tid < totalF4)
                                           b = g4[f4base + BLOCK + tid];

        __syncthreads();   // previous tile's compute done; safe to overwrite LDS
        tile4[tid] = a;
        if (tid < F4_PER_TILE - BLOCK) tile4[BLOCK + tid] = b;
        __syncthreads();   // staged tile visible

        if (row < B) {
            const float* l = tile + tid * NUM_CLASSES;  // stride-7: bank-conflict-free
            float lv[7];
            #pragma unroll
            for (int i = 0; i < NUM_CLASSES; ++i) lv[i] = l[i];

            float m = lv[0];
            #pragma unroll
            for (int i = 1; i < NUM_CLASSES; ++i) m = fmaxf(m, lv[i]);

            float s = 0.0f, w = 0.0f;
            #pragma unroll
            for (int i = 0; i < NUM_CLASSES; ++i) {
                float e = __expf(lv[i] - m);
                s += e;
                // window |i - tg| <= 1, fully predicated (no runtime indexing)
                bool in = (i >= tg - 1) && (i <= tg + 1);
                w += in ? e : 0.0f;
            }
            float total = w / s;
            acc += -__logf(total + 1e-10f);
        }
    }

    // Block reduction in double (exact enough for 4M-sum determinism vs ref).
    double d = (double)acc;
    #pragma unroll
    for (int off = 32; off > 0; off >>= 1) d += __shfl_down(d, off, 64);

    __shared__ double wsum[BLOCK / 64];
    if ((tid & 63) == 0) wsum[tid >> 6] = d;
    __syncthreads();
    if (tid == 0) {
        double blk = 0.0;
        #pragma unroll
        for (int i = 0; i < BLOCK / 64; ++i) blk += wsum[i];
        partials[blockIdx.x] = blk;
    }
}

// Finalize: reduce per-block partials, write mean as f32.
__global__ __launch_bounds__(BLOCK) void pom_finalize(const double* __restrict__ partials,
                                                      int n, float* __restrict__ out,
                                                      double invB) {
    const int tid = threadIdx.x;
    double d = 0.0;
    for (int i = tid; i < n; i += BLOCK) d += partials[i];
    #pragma unroll
    for (int off = 32; off > 0; off >>= 1) d += __shfl_down(d, off, 64);

    __shared__ double wsum[BLOCK / 64];
    if ((tid & 63) == 0) wsum[tid >> 6] = d;
    __syncthreads();
    if (tid == 0) {
        double s = 0.0;
        #pragma unroll
        for (int i = 0; i < BLOCK / 64; ++i) s += wsum[i];
        out[0] = (float)(s * invB);
    }
}

extern "C" void kernel_launch(void* const* d_in, const int* in_sizes, int n_in,
                              void* d_out, int out_size, void* d_ws, size_t ws_size,
                              hipStream_t stream) {
    const float* logits  = (const float*)d_in[0];
    const int*   targets = (const int*)d_in[1];
    const int B = in_sizes[1];              // targets count = batch
    float* out = (float*)d_out;
    double* partials = (double*)d_ws;       // NBLOCKS doubles = 16 KiB scratch

    pom_main<<<NBLOCKS, BLOCK, 0, stream>>>(logits, targets, partials, B);
    pom_finalize<<<1, BLOCK, 0, stream>>>(partials, NBLOCKS, out, 1.0 / (double)B);
}

// Round 3
// 175.407 us; speedup vs baseline: 1.0068x; 1.0068x over previous
//
#include <hip/hip_runtime.h>
#include <hip/hip_bf16.h>

#define NUM_CLASSES 7
#define ROWS_PER_TILE 256
#define BLOCK 256
#define NBLOCKS 2048
#define F4_PER_TILE (ROWS_PER_TILE * NUM_CLASSES / 4)   // 448

// Main kernel: double-buffered LDS staging (ONE barrier per tile), coalesced
// float4 loads, wave-uniform fast path (no per-lane bounds checks on full
// tiles), per-row 7-class softmax-window loss, per-block double partial.
//
// dbuf safety: per-wave program order is write(buf_i) -> barrier_i ->
// compute(buf_i) -> write(buf_{i+1}) -> barrier_{i+1} -> ... Every wave's
// compute(buf_i) precedes its barrier_{i+1}; any wave's write(buf_i) at
// iteration i+2 follows its barrier_{i+1}. One barrier per iteration suffices.
__global__ __launch_bounds__(BLOCK) void pom_main(const float* __restrict__ logits,
                                                  const int* __restrict__ targets,
                                                  double* __restrict__ partials,
                                                  int B) {
    __shared__ float4 lds4[2][F4_PER_TILE];   // 2 x 7168 B = 14 KiB

    const int tid = threadIdx.x;
    const int numTiles = (B + ROWS_PER_TILE - 1) / ROWS_PER_TILE;
    const float4* __restrict__ g4 = (const float4*)logits;
    const long long totalF4 = ((long long)B * NUM_CLASSES) / 4;

    float acc = 0.0f;
    int it = 0;

    for (int t = blockIdx.x; t < numTiles; t += gridDim.x, ++it) {
        const long long f4base = (long long)t * F4_PER_TILE;
        const int row = t * ROWS_PER_TILE + tid;
        // Wave-uniform: is this tile entirely in range? (Always true for B=4M.)
        const bool full = (f4base + F4_PER_TILE) <= totalF4 &&
                          (long long)(t + 1) * ROWS_PER_TILE <= (long long)B;

        int tg;
        float4 a, b;
        if (full) {
            tg = targets[row];
            a = g4[f4base + tid];
            b = (tid < F4_PER_TILE - BLOCK) ? g4[f4base + BLOCK + tid]
                                            : make_float4(0.f, 0.f, 0.f, 0.f);
        } else {
            tg = (row < B) ? targets[row] : 0;
            a = (f4base + tid < totalF4) ? g4[f4base + tid]
                                         : make_float4(0.f, 0.f, 0.f, 0.f);
            b = (tid < F4_PER_TILE - BLOCK && f4base + BLOCK + tid < totalF4)
                    ? g4[f4base + BLOCK + tid]
                    : make_float4(0.f, 0.f, 0.f, 0.f);
        }

        float4* buf = lds4[it & 1];
        buf[tid] = a;
        if (tid < F4_PER_TILE - BLOCK) buf[BLOCK + tid] = b;
        __syncthreads();   // the only barrier per tile

        if (row < B) {
            const float* l = (const float*)buf + tid * NUM_CLASSES;  // stride-7: conflict-free
            float lv[7];
            #pragma unroll
            for (int i = 0; i < NUM_CLASSES; ++i) lv[i] = l[i];

            float m = lv[0];
            #pragma unroll
            for (int i = 1; i < NUM_CLASSES; ++i) m = fmaxf(m, lv[i]);

            float s = 0.0f, w = 0.0f;
            #pragma unroll
            for (int i = 0; i < NUM_CLASSES; ++i) {
                float e = __expf(lv[i] - m);
                s += e;
                bool in = (i >= tg - 1) && (i <= tg + 1);   // fully predicated
                w += in ? e : 0.0f;
            }
            acc += -__logf(w / s + 1e-10f);
        }
    }

    // Block reduction in double (deterministic, exact enough vs ref).
    double d = (double)acc;
    #pragma unroll
    for (int off = 32; off > 0; off >>= 1) d += __shfl_down(d, off, 64);

    __shared__ double wsum[BLOCK / 64];
    if ((tid & 63) == 0) wsum[tid >> 6] = d;
    __syncthreads();
    if (tid == 0) {
        double blk = 0.0;
        #pragma unroll
        for (int i = 0; i < BLOCK / 64; ++i) blk += wsum[i];
        partials[blockIdx.x] = blk;
    }
}

// Finalize: reduce per-block partials, write mean as f32.
__global__ __launch_bounds__(BLOCK) void pom_finalize(const double* __restrict__ partials,
                                                      int n, float* __restrict__ out,
                                                      double invB) {
    const int tid = threadIdx.x;
    double d = 0.0;
    for (int i = tid; i < n; i += BLOCK) d += partials[i];
    #pragma unroll
    for (int off = 32; off > 0; off >>= 1) d += __shfl_down(d, off, 64);

    __shared__ double wsum[BLOCK / 64];
    if ((tid & 63) == 0) wsum[tid >> 6] = d;
    __syncthreads();
    if (tid == 0) {
        double s = 0.0;
        #pragma unroll
        for (int i = 0; i < BLOCK / 64; ++i) s += wsum[i];
        out[0] = (float)(s * invB);
    }
}

extern "C" void kernel_launch(void* const* d_in, const int* in_sizes, int n_in,
                              void* d_out, int out_size, void* d_ws, size_t ws_size,
                              hipStream_t stream) {
    const float* logits  = (const float*)d_in[0];
    const int*   targets = (const int*)d_in[1];
    const int B = in_sizes[1];              // targets count = batch
    float* out = (float*)d_out;
    double* partials = (double*)d_ws;       // NBLOCKS doubles = 16 KiB scratch

    pom_main<<<NBLOCKS, BLOCK, 0, stream>>>(logits, targets, partials, B);
    pom_finalize<<<1, BLOCK, 0, stream>>>(partials, NBLOCKS, out, 1.0 / (double)B);
}